// Round 1
// baseline (290.991 us; speedup 1.0000x reference)
//
#include <hip/hip_runtime.h>
#include <cfloat>
#include <climits>

#define NB 64
#define NA 2000
#define NA0 1600
#define NC 20
#define NM 100

__device__ __forceinline__ void anchor_geom(int a, float& axc, float& ayc, float& st, float& gx, float& gy) {
    if (a < NA0) {
        st = 16.0f;
        int x = a % 40, y = a / 40;
        gx = (float)x; gy = (float)y;
    } else {
        st = 32.0f;
        int aa = a - NA0;
        int x = aa % 20, y = aa / 20;
        gx = (float)x; gy = (float)y;
    }
    axc = (gx + 0.5f) * st;
    ayc = (gy + 0.5f) * st;
}

// pairwise IoU (gt-first area order, matches reference) + full SimOTA cost
__device__ __forceinline__ float cost_and_iou(const float4 g, int gtc, const float4 pb,
                                              float axc, float ayc, float st,
                                              float Sv, const float* __restrict__ q, size_t qb, int a,
                                              bool fgcand, bool gtv, float& iou_out) {
    float tlx = fmaxf(g.x - 0.5f * g.z, pb.x - 0.5f * pb.z);
    float tly = fmaxf(g.y - 0.5f * g.w, pb.y - 0.5f * pb.w);
    float brx = fminf(g.x + 0.5f * g.z, pb.x + 0.5f * pb.z);
    float bry = fminf(g.y + 0.5f * g.w, pb.y + 0.5f * pb.w);
    float inter = (brx - tlx) * (bry - tly);
    bool ok = (tlx < brx) && (tly < bry);
    inter = ok ? inter : 0.0f;
    float iou = inter / ((g.z * g.w + pb.z * pb.w) - inter + 1e-16f);
    iou_out = iou;
    float clsc = Sv + q[qb + (size_t)gtc * NA + a];
    bool ib = gtv && (axc > g.x - 0.5f * g.z) && (axc < g.x + 0.5f * g.z)
                  && (ayc > g.y - 0.5f * g.w) && (ayc < g.y + 0.5f * g.w);
    bool ic = gtv && (axc > g.x - 2.5f * st) && (axc < g.x + 2.5f * st)
                  && (ayc > g.y - 2.5f * st) && (ayc < g.y + 2.5f * st);
    bool inboth = ib && ic;
    bool invalid = (!fgcand) || (!gtv);
    // match reference fp add order: ((cls - 3*log) + 1e5*pen) + 1e9*inv
    float c = ((clsc - 3.0f * logf(iou + 1e-8f)) + (inboth ? 0.0f : 1e5f)) + (invalid ? 1e9f : 0.0f);
    return c;
}

__global__ __launch_bounds__(256) void k_decode(const float* __restrict__ l0, const float* __restrict__ l1,
                                                const float* __restrict__ gt_boxes, const int* __restrict__ num_gts,
                                                float4* __restrict__ dec, float* __restrict__ S, float* __restrict__ q,
                                                int* __restrict__ fgc, int* __restrict__ cnt, int* __restrict__ minm) {
    int b = blockIdx.y;
    int a = blockIdx.x * 256 + threadIdx.x;
    __shared__ float4 sgt[NM];
    __shared__ int sng;
    if (threadIdx.x < NM) {
        float4 g = ((const float4*)gt_boxes)[b * NM + threadIdx.x];
        g.x *= 640.0f; g.y *= 640.0f; g.z *= 640.0f; g.w *= 640.0f;
        sgt[threadIdx.x] = g;
    }
    if (threadIdx.x == 0) sng = num_gts[b];
    __syncthreads();
    if (a >= NA) return;

    float v[25];
    if (a < NA0) {
        const float* p = l0 + (size_t)b * 25 * NA0 + a;
#pragma unroll
        for (int c = 0; c < 25; c++) v[c] = p[(size_t)c * NA0];
    } else {
        const float* p = l1 + (size_t)b * 25 * 400 + (a - NA0);
#pragma unroll
        for (int c = 0; c < 25; c++) v[c] = p[(size_t)c * 400];
    }
    float axc, ayc, st, gx, gy;
    anchor_geom(a, axc, ayc, st, gx, gy);
    float4 pb;
    pb.x = (v[0] + gx) * st;
    pb.y = (v[1] + gy) * st;
    pb.z = expf(v[2]) * st;
    pb.w = expf(v[3]) * st;
    dec[b * NA + a] = pb;

    float sob = 1.0f / (1.0f + expf(-v[4]));
    float s = 0.0f;
#pragma unroll
    for (int c = 0; c < NC; c++) {
        float sc = 1.0f / (1.0f + expf(-v[5 + c]));
        float p = sqrtf(sc * sob);
        float lp = logf(p + 1e-12f);
        float lq = logf(1.0f - p + 1e-12f);
        s += -lq;
        q[((size_t)b * NC + c) * NA + a] = lq - lp;
    }
    S[b * NA + a] = s;

    int ng = sng;
    int f = 0;
    for (int m = 0; m < ng; m++) {
        float4 g = sgt[m];
        bool ib = (axc > g.x - 0.5f * g.z) && (axc < g.x + 0.5f * g.z)
               && (ayc > g.y - 0.5f * g.w) && (ayc < g.y + 0.5f * g.w);
        bool ic = (axc > g.x - 2.5f * st) && (axc < g.x + 2.5f * st)
               && (ayc > g.y - 2.5f * st) && (ayc < g.y + 2.5f * st);
        if (ib || ic) { f = 1; break; }
    }
    fgc[b * NA + a] = f;
    cnt[b * NA + a] = 0;
    minm[b * NA + a] = INT_MAX;
}

// one wave per (b, m) row; 4 waves per block
__global__ __launch_bounds__(256) void k_assign(const float* __restrict__ gt_boxes, const int* __restrict__ gt_classes,
                                                const int* __restrict__ num_gts, const float4* __restrict__ dec,
                                                const float* __restrict__ S, const float* __restrict__ q,
                                                const int* __restrict__ fgc, int* __restrict__ cnt, int* __restrict__ minm) {
    int wave = threadIdx.x >> 6;
    int lane = threadIdx.x & 63;
    int row = blockIdx.x * 4 + wave;
    int b = row / NM, m = row % NM;
    int ng = num_gts[b];
    if (m >= ng) return;

    float4 g = ((const float4*)gt_boxes)[b * NM + m];
    g.x *= 640.0f; g.y *= 640.0f; g.z *= 640.0f; g.w *= 640.0f;
    int tc = gt_classes[b * NM + m];
    size_t qb = (size_t)b * NC * NA;

    float ioum[32], cost[32];
#pragma unroll
    for (int j = 0; j < 32; j++) {
        int a = j * 64 + lane;
        if (a < NA) {
            float axc, ayc, st, gx, gy;
            anchor_geom(a, axc, ayc, st, gx, gy);
            float4 pb = dec[b * NA + a];
            bool fc = fgc[b * NA + a] != 0;
            float iou;
            float c = cost_and_iou(g, tc, pb, axc, ayc, st, S[b * NA + a], q, qb, a, fc, true, iou);
            cost[j] = c;
            ioum[j] = fc ? iou : 0.0f;
        } else {
            cost[j] = FLT_MAX;
            ioum[j] = -1.0f;
        }
    }

    // dk = max(1, trunc(sum of top-10 masked IoUs)) — selection in descending order (same add order as topk.sum)
    float lastv = FLT_MAX; int lasti = -1;
    float s10 = 0.0f;
    for (int k = 0; k < 10; k++) {
        float bv = -FLT_MAX; int bi = INT_MAX;
#pragma unroll
        for (int j = 0; j < 32; j++) {
            int idx = j * 64 + lane;
            float vv = ioum[j];
            bool elig = (vv < lastv) || (vv == lastv && idx > lasti);
            if (elig && (vv > bv || (vv == bv && idx < bi))) { bv = vv; bi = idx; }
        }
        for (int o = 1; o < 64; o <<= 1) {
            float ov = __shfl_xor(bv, o);
            int oi = __shfl_xor(bi, o);
            if (ov > bv || (ov == bv && oi < bi)) { bv = ov; bi = oi; }
        }
        s10 += bv; lastv = bv; lasti = bi;
    }
    int dk = (int)s10;
    if (dk < 1) dk = 1;

    // find pair at stable ascending rank dk-1
    float lc = -FLT_MAX; int li = -1;
    for (int k = 0; k < dk; k++) {
        float bv = FLT_MAX; int bi = INT_MAX;
#pragma unroll
        for (int j = 0; j < 32; j++) {
            int idx = j * 64 + lane;
            float vv = cost[j];
            bool elig = (vv > lc) || (vv == lc && idx > li);
            if (elig && (vv < bv || (vv == bv && idx < bi))) { bv = vv; bi = idx; }
        }
        for (int o = 1; o < 64; o <<= 1) {
            float ov = __shfl_xor(bv, o);
            int oi = __shfl_xor(bi, o);
            if (ov < bv || (ov == bv && oi < bi)) { bv = ov; bi = oi; }
        }
        lc = bv; li = bi;
    }

    // matching = stable rank < dk  <=>  (cost,idx) lex<= (lc,li)
#pragma unroll
    for (int j = 0; j < 32; j++) {
        int a = j * 64 + lane;
        if (a < NA) {
            bool match = (cost[j] < lc) || (cost[j] == lc && a <= li);
            if (match) {
                atomicAdd(&cnt[b * NA + a], 1);
                atomicMin(&minm[b * NA + a], m);
            }
        }
    }
}

__global__ __launch_bounds__(256) void k_resolve(const float* __restrict__ l0, const float* __restrict__ l1,
                                                 const float* __restrict__ gt_boxes, const int* __restrict__ gt_classes,
                                                 const int* __restrict__ num_gts,
                                                 const float4* __restrict__ dec, const float* __restrict__ S,
                                                 const float* __restrict__ q,
                                                 const int* __restrict__ fgc, const int* __restrict__ cnt,
                                                 const int* __restrict__ minm,
                                                 float* __restrict__ partials) {
    int idx = blockIdx.x * 256 + threadIdx.x;
    int b = idx / NA, a = idx - b * NA;

    float objv;
    if (a < NA0) objv = l0[((size_t)b * 25 + 4) * NA0 + a];
    else         objv = l1[((size_t)b * 25 + 4) * 400 + (a - NA0)];

    int c = cnt[idx];
    bool fg = c > 0;
    float fgf = fg ? 1.0f : 0.0f;
    float lobj = (fmaxf(objv, 0.0f) + log1pf(expf(-fabsf(objv)))) - objv * fgf;
    float liou = 0.0f, lcls = 0.0f;

    if (fg) {
        float axc, ayc, st, gx, gy;
        anchor_geom(a, axc, ayc, st, gx, gy);
        float4 pb = dec[idx];
        int m;
        if (c == 1) {
            m = minm[idx];
        } else {
            // conflict: best_gt = argmin_m cost (first occurrence)
            int ng = num_gts[b];
            size_t qb = (size_t)b * NC * NA;
            float Sv = S[idx];
            bool fc = fgc[idx] != 0;
            float best = FLT_MAX; m = 0;
            for (int mm = 0; mm < NM; mm++) {
                float4 g = ((const float4*)gt_boxes)[b * NM + mm];
                g.x *= 640.0f; g.y *= 640.0f; g.z *= 640.0f; g.w *= 640.0f;
                int tcm = gt_classes[b * NM + mm];
                float iou;
                float cc = cost_and_iou(g, tcm, pb, axc, ayc, st, Sv, q, qb, a, fc, mm < ng, iou);
                if (cc < best) { best = cc; m = mm; }
            }
        }
        float4 g = ((const float4*)gt_boxes)[b * NM + m];
        g.x *= 640.0f; g.y *= 640.0f; g.z *= 640.0f; g.w *= 640.0f;
        float tlx = fmaxf(pb.x - 0.5f * pb.z, g.x - 0.5f * g.z);
        float tly = fmaxf(pb.y - 0.5f * pb.w, g.y - 0.5f * g.w);
        float brx = fminf(pb.x + 0.5f * pb.z, g.x + 0.5f * g.z);
        float bry = fminf(pb.y + 0.5f * pb.w, g.y + 0.5f * g.w);
        float inter = (brx - tlx) * (bry - tly);
        bool ok = (tlx < brx) && (tly < bry);
        inter = ok ? inter : 0.0f;
        float iou = inter / ((pb.z * pb.w + g.z * g.w) - inter + 1e-16f);
        liou = 1.0f - iou * iou;
        float piou = iou;  // pred_iou: identical formula (fp add commutative)
        int tcm = gt_classes[b * NM + m];
#pragma unroll
        for (int c2 = 0; c2 < NC; c2++) {
            float x;
            if (a < NA0) x = l0[((size_t)b * 25 + 5 + c2) * NA0 + a];
            else         x = l1[((size_t)b * 25 + 5 + c2) * 400 + (a - NA0)];
            float t = (c2 == tcm) ? piou : 0.0f;
            lcls += (fmaxf(x, 0.0f) + log1pf(expf(-fabsf(x)))) - x * t;
        }
    }

    __shared__ float s0[256], s1[256], s2[256], s3[256];
    int t = threadIdx.x;
    s0[t] = lobj; s1[t] = liou; s2[t] = lcls; s3[t] = fgf;
    __syncthreads();
    for (int o = 128; o > 0; o >>= 1) {
        if (t < o) { s0[t] += s0[t + o]; s1[t] += s1[t + o]; s2[t] += s2[t + o]; s3[t] += s3[t + o]; }
        __syncthreads();
    }
    if (t == 0) {
        partials[blockIdx.x * 4 + 0] = s0[0];
        partials[blockIdx.x * 4 + 1] = s1[0];
        partials[blockIdx.x * 4 + 2] = s2[0];
        partials[blockIdx.x * 4 + 3] = s3[0];
    }
}

__global__ __launch_bounds__(256) void k_final(const float* __restrict__ partials, int nblocks,
                                               const int* __restrict__ num_gts, float* __restrict__ out) {
    __shared__ float s0[256], s1[256], s2[256], s3[256];
    int t = threadIdx.x;
    float a0 = 0, a1 = 0, a2 = 0, a3 = 0;
    for (int i = t; i < nblocks; i += 256) {
        a0 += partials[i * 4 + 0];
        a1 += partials[i * 4 + 1];
        a2 += partials[i * 4 + 2];
        a3 += partials[i * 4 + 3];
    }
    s0[t] = a0; s1[t] = a1; s2[t] = a2; s3[t] = a3;
    __syncthreads();
    for (int o = 128; o > 0; o >>= 1) {
        if (t < o) { s0[t] += s0[t + o]; s1[t] += s1[t + o]; s2[t] += s2[t + o]; s3[t] += s3[t + o]; }
        __syncthreads();
    }
    if (t == 0) {
        int sg = 0;
        for (int i = 0; i < NB; i++) sg += num_gts[i];
        float num_fg = fmaxf(s3[0], 1.0f);
        float li5 = 5.0f * (s1[0] / num_fg);
        float lo = s0[0] / num_fg;
        float lc = s2[0] / num_fg;
        out[0] = li5 + lo + lc;
        out[1] = li5;
        out[2] = lo;
        out[3] = lc;
        out[4] = num_fg / fmaxf((float)sg, 1.0f);
    }
}

extern "C" void kernel_launch(void* const* d_in, const int* in_sizes, int n_in,
                              void* d_out, int out_size, void* d_ws, size_t ws_size,
                              hipStream_t stream) {
    const float* l0 = (const float*)d_in[0];
    const float* l1 = (const float*)d_in[1];
    const float* gt_boxes = (const float*)d_in[2];
    const int* gt_classes = (const int*)d_in[3];
    const int* num_gts = (const int*)d_in[4];
    float* out = (float*)d_out;

    char* w = (char*)d_ws;
    float4* dec = (float4*)(w);                  // 128000 * 16 = 2,048,000
    float* S    = (float*)(w + 2048000);         // 512,000
    float* q    = (float*)(w + 2560000);         // 10,240,000
    int* fgc    = (int*)(w + 12800000);          // 512,000
    int* cnt    = (int*)(w + 13312000);          // 512,000
    int* minm   = (int*)(w + 13824000);          // 512,000
    float* partials = (float*)(w + 14336000);    // 500*4*4 = 8,000

    (void)n_in; (void)in_sizes; (void)out_size; (void)ws_size;

    k_decode<<<dim3(8, NB), 256, 0, stream>>>(l0, l1, gt_boxes, num_gts, dec, S, q, fgc, cnt, minm);
    k_assign<<<(NB * NM) / 4, 256, 0, stream>>>(gt_boxes, gt_classes, num_gts, dec, S, q, fgc, cnt, minm);
    k_resolve<<<(NB * NA) / 256, 256, 0, stream>>>(l0, l1, gt_boxes, gt_classes, num_gts, dec, S, q, fgc, cnt, minm, partials);
    k_final<<<1, 256, 0, stream>>>(partials, (NB * NA) / 256, num_gts, out);
}